// Round 6
// baseline (76.017 us; speedup 1.0000x reference)
//
#include <hip/hip_runtime.h>
#include <math.h>

// SOR defense: B=4, K=8192, 3D points. kNN k=2 (3 smallest incl. self).
// Outputs: masked_pc [4,8192,3] then mask [4,8192] (floats).
//
// knn inner loop broadcasts j-points via the SCALAR register file:
// s_load_dwordx16 streams 4 packed points (x,y,z,||p||^2) per scalar load;
// every VALU op reads <=1 SGPR, so the loop is exactly 8 VALU per pair
// with zero LDS traffic and ~50 VGPRs.

constexpr int B = 4;
constexpr int K = 8192;
constexpr int QPB = 256;         // threads per block
constexpr int QPT = 4;           // queries per thread
constexpr int QBLK = QPB * QPT;  // 1024 queries per block

#define BIG 3.0e38f

using f32x16 = __attribute__((ext_vector_type(16))) float;

// Exact top-3 insert via med3: for sorted e0<=e1<=e2 and candidate d, the
// 3 smallest of {e0,e1,e2,d} sorted are {min(e0,d), med3(d,e0,e1),
// med3(d,e1,e2)}. Pure selection -> exact, 3 independent VALU ops.
#define MINSERT(d, e0, e1, e2)                                  \
  do {                                                          \
    const float n0_ = fminf((e0), (d));                         \
    const float n1_ = __builtin_amdgcn_fmed3f((d), (e0), (e1)); \
    const float n2_ = __builtin_amdgcn_fmed3f((d), (e1), (e2)); \
    (e0) = n0_; (e1) = n1_; (e2) = n2_;                         \
  } while (0)

// One (point, query) update; distance expression textually identical to the
// validated R3-R5 kernels -> identical rounding -> bit-identical values.
#define PQ1(PX, PY, PZ, PW, Q)                                        \
  do {                                                                \
    const float dot_ = (qx[Q] * (PX) + qy[Q] * (PY)) + qz[Q] * (PZ);  \
    const float d_ = (qn[Q] - 2.0f * dot_) + (PW);                    \
    MINSERT(d_, e0[Q], e1[Q], e2[Q]);                                 \
  } while (0)

// Prologue: pack (x, y, z, ||p||^2) per point. Same norm expression as the
// reference's xx -> bit-identical qn and p.w everywhere downstream.
__global__ __launch_bounds__(256) void pack_kernel(
    const float* __restrict__ x, float4* __restrict__ pack) {
  const int g = blockIdx.x * 256 + threadIdx.x;  // over B*K
  const float px = x[(size_t)g * 3 + 0];
  const float py = x[(size_t)g * 3 + 1];
  const float pz = x[(size_t)g * 3 + 2];
  pack[g] = make_float4(px, py, pz, (px * px + py * py) + pz * pz);
}

template <int CHUNK>
__global__ __launch_bounds__(QPB, 4) void knn_part_kernel(
    const float4* __restrict__ pack, float* __restrict__ part) {
  constexpr int NCH = K / CHUNK;
  const int bid   = blockIdx.x;
  const int chunk = bid % NCH;
  const int rest  = bid / NCH;
  const int kc    = rest % (K / QBLK);
  const int b     = rest / (K / QBLK);
  const int tid   = threadIdx.x;

  const float4* pb = pack + (size_t)b * K;

  float qx[QPT], qy[QPT], qz[QPT], qn[QPT];
#pragma unroll
  for (int q = 0; q < QPT; ++q) {
    const float4 f = pb[kc * QBLK + q * QPB + tid];
    qx[q] = f.x; qy[q] = f.y; qz[q] = f.z; qn[q] = f.w;
  }

  float e0[QPT], e1[QPT], e2[QPT];
#pragma unroll
  for (int q = 0; q < QPT; ++q) { e0[q] = BIG; e1[q] = BIG; e2[q] = BIG; }

  // Stream the chunk's points through SGPRs: 2 x s_load_dwordx16 = 8 points
  // (x,y,z,w) per iteration. The s_waitcnt asm is data-tied to both loads so
  // uses cannot be scheduled before it. Per-iter drain stall (~200 cy) hides
  // under 4 blocks/CU of TLP; compute per iter is ~512 cy.
  const float4* pp = pb + chunk * CHUNK;
  for (int j = 0; j < CHUNK; j += 8, pp += 8) {
    f32x16 c0, c1;
    asm volatile("s_load_dwordx16 %0, %1, 0x0" : "=s"(c0) : "s"(pp));
    asm volatile("s_load_dwordx16 %0, %1, 0x0" : "=s"(c1) : "s"(pp + 4));
    asm volatile("s_waitcnt lgkmcnt(0)" : "+s"(c0), "+s"(c1));
#pragma unroll
    for (int u = 0; u < 4; ++u) {
#pragma unroll
      for (int q = 0; q < QPT; ++q) {
        PQ1(c0[4 * u + 0], c0[4 * u + 1], c0[4 * u + 2], c0[4 * u + 3], q);
      }
    }
#pragma unroll
    for (int u = 0; u < 4; ++u) {
#pragma unroll
      for (int q = 0; q < QPT; ++q) {
        PQ1(c1[4 * u + 0], c1[4 * u + 1], c1[4 * u + 2], c1[4 * u + 3], q);
      }
    }
  }

  // Transposed partials [chunk][b*K][3]: consecutive lanes write consecutive
  // 12 B -> full-line coalescing (kills the 3.5x write amplification).
#pragma unroll
  for (int q = 0; q < QPT; ++q) {
    const int k = kc * QBLK + q * QPB + tid;
    float* dst = part + ((size_t)chunk * (B * K) + (size_t)b * K + k) * 3;
    dst[0] = e0[q];
    dst[1] = e1[q];
    dst[2] = e2[q];
  }
}

// Stage 1: merge partials -> value[b,k]; per-block double sums.
template <int NCH>
__global__ __launch_bounds__(256) void sor_value_kernel(
    const float* __restrict__ part, float* __restrict__ value,
    double* __restrict__ bsum) {
  const int blk = blockIdx.x;  // b*32 + sub
  const int b   = blk >> 5;
  const int tid = threadIdx.x;
  const int k   = (blk & 31) * 256 + tid;

  const float* pp = part + (size_t)(b * K + k) * 3;
  float d0 = BIG, d1 = BIG, d2 = BIG;
#pragma unroll 4
  for (int ch = 0; ch < NCH; ++ch) {
    const float a0 = pp[0];
    const float a1 = pp[1];
    const float a2 = pp[2];
    MINSERT(a0, d0, d1, d2);
    MINSERT(a1, d0, d1, d2);
    MINSERT(a2, d0, d1, d2);
    pp += (size_t)B * K * 3;
  }
  const float v = 0.5f * (d1 + d2);  // drop self (d0), mean of 2 kNN
  value[b * K + k] = v;

  double s = (double)v, s2 = (double)v * (double)v;
  for (int off = 32; off > 0; off >>= 1) {
    s  += __shfl_down(s, off, 64);
    s2 += __shfl_down(s2, off, 64);
  }
  __shared__ double rs[4], rs2[4];
  const int wave = tid >> 6;
  if ((tid & 63) == 0) { rs[wave] = s; rs2[wave] = s2; }
  __syncthreads();
  if (tid == 0) {
    double S = 0.0, S2 = 0.0;
    for (int w = 0; w < 4; ++w) { S += rs[w]; S2 += rs2[w]; }  // fixed order
    bsum[blk * 2 + 0] = S;
    bsum[blk * 2 + 1] = S2;
  }
}

// Stage 2: threshold per batch (fixed order -> deterministic).
__global__ __launch_bounds__(64) void sor_thresh_kernel(
    const double* __restrict__ bsum, float* __restrict__ thr) {
  const int b = threadIdx.x;
  if (b < B) {
    double S = 0.0, S2 = 0.0;
    for (int w = 0; w < 32; ++w) {
      S  += bsum[(b * 32 + w) * 2 + 0];
      S2 += bsum[(b * 32 + w) * 2 + 1];
    }
    const double mean = S / (double)K;
    const double var  = (S2 - S * S / (double)K) / (double)(K - 1);
    thr[b] = (float)(mean + 1.1 * sqrt(var));
  }
}

// Stage 3: apply mask.
__global__ __launch_bounds__(256) void sor_mask_kernel(
    const float* __restrict__ x, const float* __restrict__ value,
    const float* __restrict__ thr, float* __restrict__ out) {
  const int g = blockIdx.x * 256 + threadIdx.x;  // b*K + k
  const int b = g / K;
  const float m = (value[g] <= thr[b]) ? 1.0f : 0.0f;
  out[(size_t)B * K * 3 + g] = m;
  const size_t base = (size_t)g * 3;
  out[base + 0] = x[base + 0] * m;
  out[base + 1] = x[base + 1] * m;
  out[base + 2] = x[base + 2] * m;
}

template <int NCH>
static void run(const float* x, float* out, char* ws, hipStream_t stream) {
  float4* pack = (float4*)ws;
  size_t off = (size_t)B * K * sizeof(float4);
  float* part = (float*)(ws + off);
  off += (size_t)B * K * NCH * 3 * sizeof(float);
  float* value = (float*)(ws + off);
  off += (size_t)B * K * sizeof(float);
  off = (off + 7) & ~(size_t)7;
  double* bsum = (double*)(ws + off);
  off += (size_t)B * 32 * 2 * sizeof(double);
  float* thr = (float*)(ws + off);

  pack_kernel<<<B * K / 256, 256, 0, stream>>>(x, pack);
  knn_part_kernel<K / NCH><<<B * (K / QBLK) * NCH, QPB, 0, stream>>>(pack, part);
  sor_value_kernel<NCH><<<B * 32, 256, 0, stream>>>(part, value, bsum);
  sor_thresh_kernel<<<1, 64, 0, stream>>>(bsum, thr);
  sor_mask_kernel<<<B * K / 256, 256, 0, stream>>>(x, value, thr, out);
}

extern "C" void kernel_launch(void* const* d_in, const int* in_sizes, int n_in,
                              void* d_out, int out_size, void* d_ws, size_t ws_size,
                              hipStream_t stream) {
  const float* x = (const float*)d_in[0];
  float* out = (float*)d_out;
  char* ws = (char*)d_ws;

  const size_t fixed = (size_t)B * K * sizeof(float4) +
                       (size_t)B * K * sizeof(float) + 4096;
  if (ws_size >= (size_t)B * K * 32 * 3 * sizeof(float) + fixed) {
    run<32>(x, out, ws, stream);   // 1024 blocks
  } else if (ws_size >= (size_t)B * K * 16 * 3 * sizeof(float) + fixed) {
    run<16>(x, out, ws, stream);   // 512 blocks
  } else if (ws_size >= (size_t)B * K * 8 * 3 * sizeof(float) + fixed) {
    run<8>(x, out, ws, stream);    // 256 blocks
  } else {
    run<2>(x, out, ws, stream);    // 64 blocks
  }
}

// Round 7
// 73.904 us; speedup vs baseline: 1.0286x; 1.0286x over previous
//
#include <hip/hip_runtime.h>
#include <math.h>

// SOR defense: B=4, K=8192, 3D points. kNN k=2 (3 smallest incl. self).
// Outputs: masked_pc [4,8192,3] then mask [4,8192] (floats).
//
// knn: j-points stream through SGPRs (SoA planes, s_load_dwordx8, double-
// buffered + software-pipelined); distances computed 2-points-per-instruction
// with v_pk_{mul,fma,add}_f32 (same IEEE f32 ops -> bit-identical); top-3
// kept per (query, point-parity) chain with med3 inserts, merged exactly.

constexpr int B = 4;
constexpr int K = 8192;
constexpr int BK = B * K;
constexpr int QPB = 256;         // threads per block
constexpr int QPT = 4;           // queries per thread
constexpr int QBLK = QPB * QPT;  // 1024 queries per block

#define BIG 3.0e38f

using f32x8 = __attribute__((ext_vector_type(8))) float;

// Exact top-3 insert via med3 (pure selection, exact order statistics).
#define MINSERT(d, e0, e1, e2)                                  \
  do {                                                          \
    const float n0_ = fminf((e0), (d));                         \
    const float n1_ = __builtin_amdgcn_fmed3f((d), (e0), (e1)); \
    const float n2_ = __builtin_amdgcn_fmed3f((d), (e1), (e2)); \
    (e0) = n0_; (e1) = n1_; (e2) = n2_;                         \
  } while (0)

// Packed distance for a point-pair: d = (qn - 2*((qx*px+qy*py)+qz*pz)) + pw
// per 32-bit half; rounding sequence identical to the validated R3-R6 scalar
// expression (mul, fma, fma, fma(-2), add) -> bit-identical values.
#define PK_DIST(DE, XP, YP, ZP, WP, Q)                                       \
  float2 DE;                                                                 \
  do {                                                                       \
    float2 t0_, t1_, t2_, dd_;                                               \
    asm("v_pk_mul_f32 %0, %1, %2" : "=v"(t0_) : "s"(XP), "v"(qx2[Q]));       \
    asm("v_pk_fma_f32 %0, %1, %2, %3"                                        \
        : "=v"(t1_) : "s"(YP), "v"(qy2[Q]), "v"(t0_));                       \
    asm("v_pk_fma_f32 %0, %1, %2, %3"                                        \
        : "=v"(t2_) : "s"(ZP), "v"(qz2[Q]), "v"(t1_));                       \
    asm("v_pk_fma_f32 %0, %1, %2, %3"                                        \
        : "=v"(dd_) : "v"(t2_), "v"(vm2), "v"(qn2[Q]));                      \
    asm("v_pk_add_f32 %0, %1, %2" : "=v"(DE) : "s"(WP), "v"(dd_));           \
  } while (0)

// Prologue: SoA pack. Planes X,Y,Z,W of BK floats; W = (x*x+y*y)+z*z (same
// expression as the reference xx -> bit-identical downstream).
__global__ __launch_bounds__(256) void pack_kernel(
    const float* __restrict__ x, float* __restrict__ pack) {
  const int g = blockIdx.x * 256 + threadIdx.x;  // over B*K
  const float px = x[(size_t)g * 3 + 0];
  const float py = x[(size_t)g * 3 + 1];
  const float pz = x[(size_t)g * 3 + 2];
  pack[0 * BK + g] = px;
  pack[1 * BK + g] = py;
  pack[2 * BK + g] = pz;
  pack[3 * BK + g] = (px * px + py * py) + pz * pz;
}

#define ISSUE8(BX, BY, BZ, BW, PX, PY, PZ, PW)                         \
  do {                                                                 \
    asm volatile("s_load_dwordx8 %0, %1, 0x0" : "=s"(BX) : "s"(PX));   \
    asm volatile("s_load_dwordx8 %0, %1, 0x0" : "=s"(BY) : "s"(PY));   \
    asm volatile("s_load_dwordx8 %0, %1, 0x0" : "=s"(BZ) : "s"(PZ));   \
    asm volatile("s_load_dwordx8 %0, %1, 0x0" : "=s"(BW) : "s"(PW));   \
  } while (0)

#define WAIT4(BX, BY, BZ, BW)                                          \
  asm volatile("s_waitcnt lgkmcnt(0)"                                  \
               : "+s"(BX), "+s"(BY), "+s"(BZ), "+s"(BW))

template <int CHUNK>
__global__ __launch_bounds__(QPB, 4) void knn_part_kernel(
    const float* __restrict__ pack, float* __restrict__ part) {
  constexpr int NCH = K / CHUNK;
  constexpr int NIT = CHUNK / 8;  // 8 points per pipeline stage (even count)
  const int bid   = blockIdx.x;
  const int chunk = bid % NCH;
  const int rest  = bid / NCH;
  const int kc    = rest % (K / QBLK);
  const int b     = rest / (K / QBLK);
  const int tid   = threadIdx.x;

  const float* Xpl = pack + 0 * BK + b * K;
  const float* Ypl = pack + 1 * BK + b * K;
  const float* Zpl = pack + 2 * BK + b * K;
  const float* Wpl = pack + 3 * BK + b * K;

  // Query broadcast pairs (value duplicated in both halves).
  float2 qx2[QPT], qy2[QPT], qz2[QPT], qn2[QPT];
#pragma unroll
  for (int q = 0; q < QPT; ++q) {
    const int k = kc * QBLK + q * QPB + tid;
    const float qx = Xpl[k], qy = Ypl[k], qz = Zpl[k], qn = Wpl[k];
    qx2[q] = make_float2(qx, qx);
    qy2[q] = make_float2(qy, qy);
    qz2[q] = make_float2(qz, qz);
    qn2[q] = make_float2(qn, qn);
  }
  const float2 vm2 = make_float2(-2.0f, -2.0f);

  // Top-3 chains: [query][point-parity] (parity = pk half), merged exactly.
  float e0[QPT][2], e1[QPT][2], e2[QPT][2];
#pragma unroll
  for (int q = 0; q < QPT; ++q)
#pragma unroll
    for (int p = 0; p < 2; ++p) { e0[q][p] = BIG; e1[q][p] = BIG; e2[q][p] = BIG; }

  const float* pX = Xpl + chunk * CHUNK;
  const float* pY = Ypl + chunk * CHUNK;
  const float* pZ = Zpl + chunk * CHUNK;
  const float* pW = Wpl + chunk * CHUNK;

  f32x8 ax, ay, az, aw, bx, by, bz, bw;

#define COMPUTE8(BX, BY, BZ, BW)                                        \
  do {                                                                  \
    _Pragma("unroll")                                                   \
    for (int p = 0; p < 4; ++p) {                                       \
      const float2 Xp = make_float2((BX)[2 * p], (BX)[2 * p + 1]);      \
      const float2 Yp = make_float2((BY)[2 * p], (BY)[2 * p + 1]);      \
      const float2 Zp = make_float2((BZ)[2 * p], (BZ)[2 * p + 1]);      \
      const float2 Wp = make_float2((BW)[2 * p], (BW)[2 * p + 1]);      \
      _Pragma("unroll")                                                 \
      for (int q = 0; q < QPT; ++q) {                                   \
        PK_DIST(de, Xp, Yp, Zp, Wp, q);                                 \
        MINSERT(de.x, e0[q][0], e1[q][0], e2[q][0]);                    \
        MINSERT(de.y, e0[q][1], e1[q][1], e2[q][1]);                    \
      }                                                                 \
    }                                                                   \
  } while (0)

  ISSUE8(ax, ay, az, aw, pX, pY, pZ, pW);
  for (int it = 0; it < NIT; it += 2) {
    WAIT4(ax, ay, az, aw);
    ISSUE8(bx, by, bz, bw, pX + 8, pY + 8, pZ + 8, pW + 8);
    __builtin_amdgcn_sched_barrier(0);
    COMPUTE8(ax, ay, az, aw);

    WAIT4(bx, by, bz, bw);
    if (it + 2 < NIT) {
      ISSUE8(ax, ay, az, aw, pX + 16, pY + 16, pZ + 16, pW + 16);
    }
    __builtin_amdgcn_sched_barrier(0);
    COMPUTE8(bx, by, bz, bw);

    pX += 16; pY += 16; pZ += 16; pW += 16;
  }

  // Merge parity chains (exact multiset top-3), write transposed partials
  // [chunk][b*K][3]: consecutive lanes -> consecutive 12 B (coalesced).
#pragma unroll
  for (int q = 0; q < QPT; ++q) {
    MINSERT(e0[q][1], e0[q][0], e1[q][0], e2[q][0]);
    MINSERT(e1[q][1], e0[q][0], e1[q][0], e2[q][0]);
    MINSERT(e2[q][1], e0[q][0], e1[q][0], e2[q][0]);
    const int k = kc * QBLK + q * QPB + tid;
    float* dst = part + ((size_t)chunk * BK + (size_t)b * K + k) * 3;
    dst[0] = e0[q][0];
    dst[1] = e1[q][0];
    dst[2] = e2[q][0];
  }
#undef COMPUTE8
}

// Stage 1: merge partials -> value[b,k]; per-block double sums.
template <int NCH>
__global__ __launch_bounds__(256) void sor_value_kernel(
    const float* __restrict__ part, float* __restrict__ value,
    double* __restrict__ bsum) {
  const int blk = blockIdx.x;  // b*32 + sub
  const int b   = blk >> 5;
  const int tid = threadIdx.x;
  const int k   = (blk & 31) * 256 + tid;

  const float* pp = part + (size_t)(b * K + k) * 3;
  float d0 = BIG, d1 = BIG, d2 = BIG;
#pragma unroll 4
  for (int ch = 0; ch < NCH; ++ch) {
    const float a0 = pp[0];
    const float a1 = pp[1];
    const float a2 = pp[2];
    MINSERT(a0, d0, d1, d2);
    MINSERT(a1, d0, d1, d2);
    MINSERT(a2, d0, d1, d2);
    pp += (size_t)BK * 3;
  }
  const float v = 0.5f * (d1 + d2);  // drop self (d0), mean of 2 kNN
  value[b * K + k] = v;

  double s = (double)v, s2 = (double)v * (double)v;
  for (int off = 32; off > 0; off >>= 1) {
    s  += __shfl_down(s, off, 64);
    s2 += __shfl_down(s2, off, 64);
  }
  __shared__ double rs[4], rs2[4];
  const int wave = tid >> 6;
  if ((tid & 63) == 0) { rs[wave] = s; rs2[wave] = s2; }
  __syncthreads();
  if (tid == 0) {
    double S = 0.0, S2 = 0.0;
    for (int w = 0; w < 4; ++w) { S += rs[w]; S2 += rs2[w]; }  // fixed order
    bsum[blk * 2 + 0] = S;
    bsum[blk * 2 + 1] = S2;
  }
}

// Stage 2: threshold (recomputed per block, fixed order -> deterministic,
// identical across blocks) + mask apply.
__global__ __launch_bounds__(256) void sor_mask_kernel(
    const float* __restrict__ x, const float* __restrict__ value,
    const double* __restrict__ bsum, float* __restrict__ out) {
  const int g = blockIdx.x * 256 + threadIdx.x;  // b*K + k
  const int b = g / K;  // constant within a block (256 | K)

  __shared__ float sthr;
  if (threadIdx.x == 0) {
    double S = 0.0, S2 = 0.0;
    for (int w = 0; w < 32; ++w) {
      S  += bsum[(b * 32 + w) * 2 + 0];
      S2 += bsum[(b * 32 + w) * 2 + 1];
    }
    const double mean = S / (double)K;
    const double var  = (S2 - S * S / (double)K) / (double)(K - 1);
    sthr = (float)(mean + 1.1 * sqrt(var));
  }
  __syncthreads();

  const float m = (value[g] <= sthr) ? 1.0f : 0.0f;
  out[(size_t)BK * 3 + g] = m;
  const size_t base = (size_t)g * 3;
  out[base + 0] = x[base + 0] * m;
  out[base + 1] = x[base + 1] * m;
  out[base + 2] = x[base + 2] * m;
}

template <int NCH>
static void run(const float* x, float* out, char* ws, hipStream_t stream) {
  float* pack = (float*)ws;
  size_t off = (size_t)4 * BK * sizeof(float);
  float* part = (float*)(ws + off);
  off += (size_t)BK * NCH * 3 * sizeof(float);
  float* value = (float*)(ws + off);
  off += (size_t)BK * sizeof(float);
  off = (off + 7) & ~(size_t)7;
  double* bsum = (double*)(ws + off);

  pack_kernel<<<BK / 256, 256, 0, stream>>>(x, pack);
  knn_part_kernel<K / NCH><<<B * (K / QBLK) * NCH, QPB, 0, stream>>>(pack, part);
  sor_value_kernel<NCH><<<B * 32, 256, 0, stream>>>(part, value, bsum);
  sor_mask_kernel<<<BK / 256, 256, 0, stream>>>(x, value, bsum, out);
}

extern "C" void kernel_launch(void* const* d_in, const int* in_sizes, int n_in,
                              void* d_out, int out_size, void* d_ws, size_t ws_size,
                              hipStream_t stream) {
  const float* x = (const float*)d_in[0];
  float* out = (float*)d_out;
  char* ws = (char*)d_ws;

  const size_t fixed = (size_t)4 * BK * sizeof(float) +
                       (size_t)BK * sizeof(float) + 4096;
  if (ws_size >= (size_t)BK * 32 * 3 * sizeof(float) + fixed) {
    run<32>(x, out, ws, stream);   // 1024 blocks
  } else if (ws_size >= (size_t)BK * 8 * 3 * sizeof(float) + fixed) {
    run<8>(x, out, ws, stream);    // 256 blocks
  } else {
    run<2>(x, out, ws, stream);    // 64 blocks
  }
}